// Round 5
// baseline (80.281 us; speedup 1.0000x reference)
//
#include <hip/hip_runtime.h>
#include <hip/hip_cooperative_groups.h>
#include <math.h>

namespace cg = cooperative_groups;

#define BATCH 4
#define CH 128
#define NOSC 128
#define TK 128
#define NAUD 32768
#define NVS 129          // virtual segments: 0=head, 1..127=interior k=vs-1, 128=tail

// seg tuple (8 floats, 32B): {f0h, dfh, cRev, a0, da, pad, pad, pad}
//   rev(t) = cRev + jp1*f0h + dfh*jsq ;  amp(t) = a0 + da*w ;  osc = amp*sin(2*pi*rev)

// One cooperative kernel, 512 blocks x 256 threads.
// Phase A: block j -> (b,o)=j : dots + f64 phase scan -> seg tuples.
// grid.sync()
// Phase B: block j -> batch b=j>>7, tiles {2u, 2u+1}, u=j&127 : synthesize + reduce.
__global__ __launch_bounds__(256) void osc_fused(
    const float* __restrict__ x, const float* __restrict__ W,
    const float* __restrict__ bvec, const float* __restrict__ baselines,
    float* __restrict__ seg, float* __restrict__ out)
{
    const int j = blockIdx.x;
    const int tid = threadIdx.x;
    const int b = j >> 7, o = j & 127;
    const int k = tid & 127;

    // ---------------- Phase A ----------------
    {
        // wave-uniform channel-half base -> W reads become scalar s_loads
        const int c0 = __builtin_amdgcn_readfirstlane(tid >> 7) * 64;
        const float* __restrict__ Wr = W + (2*o)*CH;
        const float* __restrict__ Wi = Wr + CH;
        const float* xb = x + b*CH*TK + k;

        float re = 0.f, im = 0.f;
        {
            float xv[32];
            #pragma unroll
            for (int u = 0; u < 32; ++u) xv[u] = xb[(c0+u)*TK];
            #pragma unroll
            for (int u = 0; u < 32; ++u) { re = fmaf(xv[u], Wr[c0+u], re); im = fmaf(xv[u], Wi[c0+u], im); }
            #pragma unroll
            for (int u = 0; u < 32; ++u) xv[u] = xb[(c0+32+u)*TK];
            #pragma unroll
            for (int u = 0; u < 32; ++u) { re = fmaf(xv[u], Wr[c0+32+u], re); im = fmaf(xv[u], Wi[c0+32+u], im); }
        }

        __shared__ float sRe[256], sIm[256];
        sRe[tid] = re; sIm[tid] = im;
        __syncthreads();

        __shared__ float fsh[TK], ash[TK];
        __shared__ double wtot;
        float fr = 0.f, amp = 0.f;
        if (tid < 128) {
            float rr = sRe[tid] + sRe[tid+128] + bvec[2*o];
            float ii = sIm[tid] + sIm[tid+128] + bvec[2*o+1];
            rr = fmaf(rr, 0.01f, baselines[2*o]);
            ii = fmaf(ii, 0.01f, baselines[2*o+1]);
            const float BASEF  = 40.0f/11025.0f;
            const float RANGEF = 8960.0f/11025.0f;
            amp = fmaf(fmaf(rr, rr, ii*ii), RANGEF, BASEF);
            float th = atan2f(ii, rr) * (1.0f/3.14159265358979323846f);
            fr = th*th;
            fsh[k] = fr; ash[k] = amp;
        }
        __syncthreads();

        double ev = 0.0;
        if (tid < 128) {
            // segment freq-sum scan (f64), closed form per 256-sample segment
            ev = (k == 0) ? 128.0*(double)fr
                          : 128.0*((double)fsh[k-1] + (double)fr);
            const int lane = tid & 63;
            #pragma unroll
            for (int d = 1; d < 64; d <<= 1) {
                double up = __shfl_up(ev, d);
                if (lane >= d) ev += up;
            }
            if (tid == 63) wtot = ev;
        }
        __syncthreads();
        if (tid < 128) {
            if (tid >= 64) ev += wtot;
            double xrev = ev * 0.5;                    // phase base in revolutions
            float cRev = (float)(xrev - floor(xrev)); // mod 1 rev, f64 once

            float* base = seg + ((size_t)(b*NVS)*NOSC + o)*8;
            const int vs = k + 1;   // interior k<=126; tail vs=128 from k==127
            float f0h = 0.5f*fr;
            float dfh = (k <= 126) ? 0.5f*(fsh[k+1] - fr) : 0.0f;
            float da  = (k <= 126) ? (ash[k+1] - amp) : 0.0f;
            float* p = base + (size_t)vs*NOSC*8;
            *(float4*)p = make_float4(f0h, dfh, cRev, amp);
            p[4] = da;
            if (k == 0) {   // head vs=0: clamped to knot 0, phase base 0
                *(float4*)base = make_float4(f0h, 0.0f, 0.0f, amp);
                base[4] = 0.0f;
            }
        }
    }

    cg::this_grid().sync();   // seg visible device-wide

    // ---------------- Phase B ----------------
    {
        __shared__ float4 tup[256];
        __shared__ float red[256];
        const int s = tid & 127;
        const int g = tid >> 7;
        const int u2 = o;   // j & 127

        for (int tt = 0; tt < 2; ++tt) {
            const int tile = 2*u2 + tt;
            int vs;
            if (tile == 0)        vs = 0;
            else if (tile == 255) vs = 128;
            else                  vs = ((tile - 1) >> 1) + 1;
            const int jint = s + 1 + ((tile != 0 && tile != 255 && !(tile & 1)) ? 128 : 0);
            const float jp1 = (float)jint;
            const float jsq = jp1*jp1*(1.0f/512.0f);
            const float w   = (2.0f*jp1 - 1.0f)*(1.0f/512.0f);

            // one fully-parallel coalesced shot: 256 lanes x 16B = all 128 tuples (4KB)
            const float4* src = (const float4*)(seg + ((size_t)(b*NVS + vs)*NOSC)*8);
            tup[tid] = src[tid];
            __syncthreads();

            float acc = 0.0f;
            const float* basep = (const float*)&tup[g*128];  // this half's 64 tuples
            #pragma unroll 8
            for (int i = 0; i < 64; ++i) {
                float4 v = *(const float4*)(basep + i*8);    // broadcast ds_read_b128
                float da = basep[i*8 + 4];
                float rev = fmaf(v.y, jsq, fmaf(jp1, v.x, v.z));
                float fr_;
                asm("v_fract_f32 %0, %1" : "=v"(fr_) : "v"(rev));   // rev mod 1
                float sn;
                asm("v_sin_f32 %0, %1" : "=v"(sn) : "v"(fr_));      // sin(2*pi*frac)
                acc = fmaf(fmaf(da, w, v.w), sn, acc);
            }

            red[tid] = acc;
            __syncthreads();
            if (tid < 128)
                out[b*NAUD + tile*128 + tid] = red[tid] + red[tid + 128];
            __syncthreads();   // protect tup/red before next tile overwrites
        }
    }
}

extern "C" void kernel_launch(void* const* d_in, const int* in_sizes, int n_in,
                              void* d_out, int out_size, void* d_ws, size_t ws_size,
                              hipStream_t stream)
{
    const float* x         = (const float*)d_in[0];
    const float* W         = (const float*)d_in[1];
    const float* bvec      = (const float*)d_in[2];
    const float* baselines = (const float*)d_in[3];
    float* out = (float*)d_out;
    float* seg = (float*)d_ws;   // 4*129*128*8*4B = 2.11 MiB

    void* args[] = { (void*)&x, (void*)&W, (void*)&bvec, (void*)&baselines,
                     (void*)&seg, (void*)&out };
    hipLaunchCooperativeKernel((const void*)osc_fused,
                               dim3(BATCH*NOSC), dim3(256), args, 0, stream);
}

// Round 7
// 15.552 us; speedup vs baseline: 5.1622x; 5.1622x over previous
//
#include <hip/hip_runtime.h>
#include <math.h>

#define BATCH 4
#define CH 128
#define NOSC 128
#define TK 128
#define NAUD 32768
#define NVS 129          // virtual segments: 0=head, 1..127=interior k=vs-1, 128=tail

// seg tuple (8 floats, 32B): {f0h, dfh, cRev, a0, da, pad, pad, pad}
//   rev(t) = cRev + jp1*f0h + dfh*jsq ;  amp(t) = a0 + da*w ;  osc = amp*sin(2*pi*rev)

// ---------------- Stage 1: dots + phase scan -> per-segment tuples ----------------
// One block per (b,o); 512 threads = 128 knots x 4 channel-groups of 32.
__global__ __launch_bounds__(512) void osc1_kernel(
    const float* __restrict__ x, const float* __restrict__ W,
    const float* __restrict__ bvec, const float* __restrict__ baselines,
    float* __restrict__ seg)
{
    const int blk = blockIdx.x;
    const int b = blk >> 7, o = blk & 127;
    const int tid = threadIdx.x;
    const int k = tid & 127;
    // wave-uniform channel-group base -> W reads become scalar s_loads
    const int c0 = __builtin_amdgcn_readfirstlane(tid >> 7) * 32;

    const float* __restrict__ Wr = W + (2*o)*CH;   // uniform addresses
    const float* __restrict__ Wi = Wr + CH;
    const float* xb = x + b*CH*TK + k;

    // 32 channels per thread, one fully-in-flight load batch
    float re = 0.f, im = 0.f;
    {
        float xv[32];
        #pragma unroll
        for (int u = 0; u < 32; ++u) xv[u] = xb[(c0+u)*TK];
        #pragma unroll
        for (int u = 0; u < 32; ++u) { re = fmaf(xv[u], Wr[c0+u], re); im = fmaf(xv[u], Wi[c0+u], im); }
    }

    __shared__ float sRe[512], sIm[512];
    sRe[tid] = re; sIm[tid] = im;
    __syncthreads();

    __shared__ float fsh[TK], ash[TK];
    __shared__ double wtot;
    float fr = 0.f, amp = 0.f;
    if (tid < 128) {
        float rr = sRe[tid] + sRe[tid+128] + sRe[tid+256] + sRe[tid+384] + bvec[2*o];
        float ii = sIm[tid] + sIm[tid+128] + sIm[tid+256] + sIm[tid+384] + bvec[2*o+1];
        rr = fmaf(rr, 0.01f, baselines[2*o]);
        ii = fmaf(ii, 0.01f, baselines[2*o+1]);
        const float BASEF  = 40.0f/11025.0f;
        const float RANGEF = 8960.0f/11025.0f;
        amp = fmaf(fmaf(rr, rr, ii*ii), RANGEF, BASEF);
        float th = atan2f(ii, rr) * (1.0f/3.14159265358979323846f);
        fr = th*th;
        fsh[k] = fr; ash[k] = amp;
    }
    __syncthreads();

    double ev = 0.0;
    if (tid < 128) {
        // segment freq-sum scan (f64), closed form per 256-sample segment
        ev = (k == 0) ? 128.0*(double)fr
                      : 128.0*((double)fsh[k-1] + (double)fr);
        const int lane = tid & 63;
        #pragma unroll
        for (int d = 1; d < 64; d <<= 1) {
            double up = __shfl_up(ev, d);
            if (lane >= d) ev += up;
        }
        if (tid == 63) wtot = ev;
    }
    __syncthreads();
    if (tid < 128) {
        if (tid >= 64) ev += wtot;
        double xrev = ev * 0.5;                    // phase base in revolutions
        float cRev = (float)(xrev - floor(xrev)); // mod 1 rev, f64 once

        float* base = seg + ((size_t)(b*NVS)*NOSC + o)*8;
        const int vs = k + 1;   // interior k<=126; tail vs=128 from k==127
        float f0h = 0.5f*fr;
        float dfh = (k <= 126) ? 0.5f*(fsh[k+1] - fr) : 0.0f;
        float da  = (k <= 126) ? (ash[k+1] - amp) : 0.0f;
        float* p = base + (size_t)vs*NOSC*8;
        *(float4*)p = make_float4(f0h, dfh, cRev, amp);
        p[4] = da;
        if (k == 0) {   // head vs=0: clamped to knot 0, phase base 0
            *(float4*)base = make_float4(f0h, 0.0f, 0.0f, amp);
            base[4] = 0.0f;
        }
    }
}

// ---------------- Stage 2: LDS-staged synthesize + in-block osc reduce ----------------
// One block per (b, z): z=0 -> head(128)+tail(128) samples; z=1..127 -> interior
// segment u=z (256 samples, uniform vs). 512 thr = 256 sample-slots x 2 osc-halves.
// NOTE: one vs-slice = 128 osc x 8 floats = 256 float4 (1024 floats, 4KB).
__global__ __launch_bounds__(512) void osc2_kernel(
    const float* __restrict__ seg, float* __restrict__ out)
{
    const int blk = blockIdx.x;
    const int b   = blk >> 7;
    const int z   = blk & 127;
    const int tid = threadIdx.x;
    const int s   = tid & 255;      // sample slot in block
    const int g   = tid >> 8;       // osc half (64 each)

    __shared__ float4 tupA[256];    // full vs-slice for head/interior
    __shared__ float4 tupB[256];    // vs=128 (tail) slice, only for z==0
    __shared__ float  red[512];

    int t;            // output sample index
    float jp1;
    const float4* srcA = (const float4*)(seg + ((size_t)(b*NVS) + (z == 0 ? 0 : z))*NOSC*8);
    if (z == 0) {
        const float4* srcB = (const float4*)(seg + ((size_t)(b*NVS) + 128)*NOSC*8);
        if (tid < 256) tupA[tid]       = srcA[tid];
        else           tupB[tid - 256] = srcB[tid - 256];
        t   = (s < 128) ? s : (NAUD - 256 + s);
        jp1 = (float)((s & 127) + 1);
    } else {
        if (tid < 256) tupA[tid] = srcA[tid];
        t   = (2*z - 1)*128 + s;
        jp1 = (float)(s + 1);
    }
    __syncthreads();

    const float jsq = jp1*jp1*(1.0f/512.0f);
    const float w   = (2.0f*jp1 - 1.0f)*(1.0f/512.0f);

    // this half's 64 tuples = 128 float4 starting at g*128
    const float* basep = (const float*)((z == 0 && s >= 128) ? &tupB[g*128] : &tupA[g*128]);
    float acc = 0.0f;
    #pragma unroll 8
    for (int i = 0; i < 64; ++i) {
        float4 v = *(const float4*)(basep + i*8);    // broadcast ds_read_b128
        float da = basep[i*8 + 4];
        float rev = fmaf(v.y, jsq, fmaf(jp1, v.x, v.z));
        float fr_;
        asm("v_fract_f32 %0, %1" : "=v"(fr_) : "v"(rev));   // rev mod 1
        float sn;
        asm("v_sin_f32 %0, %1" : "=v"(sn) : "v"(fr_));      // sin(2*pi*frac)
        acc = fmaf(fmaf(da, w, v.w), sn, acc);
    }

    red[tid] = acc;
    __syncthreads();
    if (tid < 256)
        out[b*NAUD + t] = red[tid] + red[tid + 256];
}

extern "C" void kernel_launch(void* const* d_in, const int* in_sizes, int n_in,
                              void* d_out, int out_size, void* d_ws, size_t ws_size,
                              hipStream_t stream)
{
    const float* x         = (const float*)d_in[0];
    const float* W         = (const float*)d_in[1];
    const float* bvec      = (const float*)d_in[2];
    const float* baselines = (const float*)d_in[3];
    float* out = (float*)d_out;
    float* seg = (float*)d_ws;   // 4*129*128*8*4B = 2.11 MiB

    osc1_kernel<<<BATCH*NOSC, 512, 0, stream>>>(x, W, bvec, baselines, seg);
    osc2_kernel<<<BATCH*128, 512, 0, stream>>>(seg, out);
}

// Round 8
// 15.118 us; speedup vs baseline: 5.3104x; 1.0287x over previous
//
#include <hip/hip_runtime.h>
#include <math.h>

#define BATCH 4
#define CH 128
#define NOSC 128
#define TK 128
#define NAUD 32768
#define NVS 129          // virtual segments: 0=head, 1..127=interior k=vs-1, 128=tail

// seg tuple (8 floats, 32B): {f0h, dfh, cRev, a0, da, pad, pad, pad}
//   rev(j) = cRev + jp1*f0h + dfh*jp1^2/512 ;  amp(j) = a0 + da*(2*jp1-1)/512

// ---------------- Stage 1: dots + phase scan -> per-segment tuples ----------------
// One block per (b,o); 512 threads = 128 knots x 4 channel-groups of 32.
__global__ __launch_bounds__(512) void osc1_kernel(
    const float* __restrict__ x, const float* __restrict__ W,
    const float* __restrict__ bvec, const float* __restrict__ baselines,
    float* __restrict__ seg)
{
    const int blk = blockIdx.x;
    const int b = blk >> 7, o = blk & 127;
    const int tid = threadIdx.x;
    const int k = tid & 127;
    // wave-uniform channel-group base -> W reads become scalar s_loads
    const int c0 = __builtin_amdgcn_readfirstlane(tid >> 7) * 32;

    const float* __restrict__ Wr = W + (2*o)*CH;   // uniform addresses
    const float* __restrict__ Wi = Wr + CH;
    const float* xb = x + b*CH*TK + k;

    // 32 channels per thread, one fully-in-flight load batch
    float re = 0.f, im = 0.f;
    {
        float xv[32];
        #pragma unroll
        for (int u = 0; u < 32; ++u) xv[u] = xb[(c0+u)*TK];
        #pragma unroll
        for (int u = 0; u < 32; ++u) { re = fmaf(xv[u], Wr[c0+u], re); im = fmaf(xv[u], Wi[c0+u], im); }
    }

    __shared__ float sRe[512], sIm[512];
    sRe[tid] = re; sIm[tid] = im;
    __syncthreads();

    __shared__ float fsh[TK], ash[TK];
    __shared__ double wtot;
    float fr = 0.f, amp = 0.f;
    if (tid < 128) {
        float rr = sRe[tid] + sRe[tid+128] + sRe[tid+256] + sRe[tid+384] + bvec[2*o];
        float ii = sIm[tid] + sIm[tid+128] + sIm[tid+256] + sIm[tid+384] + bvec[2*o+1];
        rr = fmaf(rr, 0.01f, baselines[2*o]);
        ii = fmaf(ii, 0.01f, baselines[2*o+1]);
        const float BASEF  = 40.0f/11025.0f;
        const float RANGEF = 8960.0f/11025.0f;
        amp = fmaf(fmaf(rr, rr, ii*ii), RANGEF, BASEF);
        float th = atan2f(ii, rr) * (1.0f/3.14159265358979323846f);
        fr = th*th;
        fsh[k] = fr; ash[k] = amp;
    }
    __syncthreads();

    double ev = 0.0;
    if (tid < 128) {
        // segment freq-sum scan (f64), closed form per 256-sample segment
        ev = (k == 0) ? 128.0*(double)fr
                      : 128.0*((double)fsh[k-1] + (double)fr);
        const int lane = tid & 63;
        #pragma unroll
        for (int d = 1; d < 64; d <<= 1) {
            double up = __shfl_up(ev, d);
            if (lane >= d) ev += up;
        }
        if (tid == 63) wtot = ev;
    }
    __syncthreads();
    if (tid < 128) {
        if (tid >= 64) ev += wtot;
        double xrev = ev * 0.5;                    // phase base in revolutions
        float cRev = (float)(xrev - floor(xrev)); // mod 1 rev, f64 once

        float* base = seg + ((size_t)(b*NVS)*NOSC + o)*8;
        const int vs = k + 1;   // interior k<=126; tail vs=128 from k==127
        float f0h = 0.5f*fr;
        float dfh = (k <= 126) ? 0.5f*(fsh[k+1] - fr) : 0.0f;
        float da  = (k <= 126) ? (ash[k+1] - amp) : 0.0f;
        float* p = base + (size_t)vs*NOSC*8;
        *(float4*)p = make_float4(f0h, dfh, cRev, amp);
        p[4] = da;
        if (k == 0) {   // head vs=0: clamped to knot 0, phase base 0
            *(float4*)base = make_float4(f0h, 0.0f, 0.0f, amp);
            base[4] = 0.0f;
        }
    }
}

// ---------------- Stage 2: 4-samples-per-tuple-read synthesize ----------------
// One block per (b, z): z=1..127 -> interior segment (256 samples, uniform vs=z);
// z=0 -> head 128 (vs=0) + tail 128 (vs=128).
// 512 thr = 64 sample-slots x 8 osc-groups of 16. Each thread: 16 osc x 4 samples.
// One vs-slice = 128 osc x 8 floats = 256 float4 (4KB).
__global__ __launch_bounds__(512) void osc2_kernel(
    const float* __restrict__ seg, float* __restrict__ out)
{
    const int blk = blockIdx.x;
    const int b   = blk >> 7;
    const int z   = blk & 127;
    const int tid = threadIdx.x;
    const int s   = tid & 63;       // sample slot
    const int g   = tid >> 6;       // osc group (16 osc)

    __shared__ float4 tupA[256];
    __shared__ float4 tupB[256];    // only used by z==0 (tail)
    __shared__ float  red[8][256];

    const float4* srcA = (const float4*)(seg + ((size_t)(b*NVS) + (z == 0 ? 0 : z))*NOSC*8);
    if (z == 0) {
        const float4* srcB = (const float4*)(seg + ((size_t)(b*NVS) + 128)*NOSC*8);
        if (tid < 256) tupA[tid]       = srcA[tid];
        else           tupB[tid - 256] = srcB[tid - 256];
    } else {
        if (tid < 256) tupA[tid] = srcA[tid];
    }
    __syncthreads();

    float acc0 = 0.f, acc1 = 0.f, acc2 = 0.f, acc3 = 0.f;
    const float* bpA = (const float*)&tupA[g*32];   // group's 16 tuples
    const float* bpB = (const float*)&tupB[g*32];

    if (z != 0) {
        // samples q = 64m + s, jp1 = q+1
        float jp1_[4], jsq_[4], w_[4];
        #pragma unroll
        for (int m = 0; m < 4; ++m) {
            float jp1 = (float)(64*m + s + 1);
            jp1_[m] = jp1;
            jsq_[m] = jp1*jp1*(1.0f/512.0f);
            w_[m]   = (2.0f*jp1 - 1.0f)*(1.0f/512.0f);
        }
        #pragma unroll
        for (int i = 0; i < 16; ++i) {
            float4 v = *(const float4*)(bpA + i*8);
            float da = bpA[i*8 + 4];
            float fr_, sn;
            float rev0 = fmaf(v.y, jsq_[0], fmaf(jp1_[0], v.x, v.z));
            asm("v_fract_f32 %0, %1" : "=v"(fr_) : "v"(rev0));
            asm("v_sin_f32 %0, %1"   : "=v"(sn)  : "v"(fr_));
            acc0 = fmaf(fmaf(da, w_[0], v.w), sn, acc0);
            float rev1 = fmaf(v.y, jsq_[1], fmaf(jp1_[1], v.x, v.z));
            asm("v_fract_f32 %0, %1" : "=v"(fr_) : "v"(rev1));
            asm("v_sin_f32 %0, %1"   : "=v"(sn)  : "v"(fr_));
            acc1 = fmaf(fmaf(da, w_[1], v.w), sn, acc1);
            float rev2 = fmaf(v.y, jsq_[2], fmaf(jp1_[2], v.x, v.z));
            asm("v_fract_f32 %0, %1" : "=v"(fr_) : "v"(rev2));
            asm("v_sin_f32 %0, %1"   : "=v"(sn)  : "v"(fr_));
            acc2 = fmaf(fmaf(da, w_[2], v.w), sn, acc2);
            float rev3 = fmaf(v.y, jsq_[3], fmaf(jp1_[3], v.x, v.z));
            asm("v_fract_f32 %0, %1" : "=v"(fr_) : "v"(rev3));
            asm("v_sin_f32 %0, %1"   : "=v"(sn)  : "v"(fr_));
            acc3 = fmaf(fmaf(da, w_[3], v.w), sn, acc3);
        }
    } else {
        // m=0,1: head (vs=0), jp1 = s+1+64m ; m=2,3: tail (vs=128), jp1 = s+1+64(m-2)
        float jp1_[2], jsq_[2], w_[2];
        #pragma unroll
        for (int m = 0; m < 2; ++m) {
            float jp1 = (float)(64*m + s + 1);
            jp1_[m] = jp1;
            jsq_[m] = jp1*jp1*(1.0f/512.0f);
            w_[m]   = (2.0f*jp1 - 1.0f)*(1.0f/512.0f);
        }
        #pragma unroll
        for (int i = 0; i < 16; ++i) {
            float4 vA = *(const float4*)(bpA + i*8);
            float daA = bpA[i*8 + 4];
            float4 vB = *(const float4*)(bpB + i*8);
            float daB = bpB[i*8 + 4];
            float fr_, sn;
            float rev0 = fmaf(vA.y, jsq_[0], fmaf(jp1_[0], vA.x, vA.z));
            asm("v_fract_f32 %0, %1" : "=v"(fr_) : "v"(rev0));
            asm("v_sin_f32 %0, %1"   : "=v"(sn)  : "v"(fr_));
            acc0 = fmaf(fmaf(daA, w_[0], vA.w), sn, acc0);
            float rev1 = fmaf(vA.y, jsq_[1], fmaf(jp1_[1], vA.x, vA.z));
            asm("v_fract_f32 %0, %1" : "=v"(fr_) : "v"(rev1));
            asm("v_sin_f32 %0, %1"   : "=v"(sn)  : "v"(fr_));
            acc1 = fmaf(fmaf(daA, w_[1], vA.w), sn, acc1);
            float rev2 = fmaf(vB.y, jsq_[0], fmaf(jp1_[0], vB.x, vB.z));
            asm("v_fract_f32 %0, %1" : "=v"(fr_) : "v"(rev2));
            asm("v_sin_f32 %0, %1"   : "=v"(sn)  : "v"(fr_));
            acc2 = fmaf(fmaf(daB, w_[0], vB.w), sn, acc2);
            float rev3 = fmaf(vB.y, jsq_[1], fmaf(jp1_[1], vB.x, vB.z));
            asm("v_fract_f32 %0, %1" : "=v"(fr_) : "v"(rev3));
            asm("v_sin_f32 %0, %1"   : "=v"(sn)  : "v"(fr_));
            acc3 = fmaf(fmaf(daB, w_[1], vB.w), sn, acc3);
        }
    }

    red[g][      s] = acc0;
    red[g][ 64 + s] = acc1;
    red[g][128 + s] = acc2;
    red[g][192 + s] = acc3;
    __syncthreads();

    if (tid < 256) {
        float v = 0.f;
        #pragma unroll
        for (int gg = 0; gg < 8; ++gg) v += red[gg][tid];
        int t = (z != 0) ? ((2*z - 1)*128 + tid)
                         : ((tid < 128) ? tid : (NAUD - 256 + tid));
        out[b*NAUD + t] = v;
    }
}

extern "C" void kernel_launch(void* const* d_in, const int* in_sizes, int n_in,
                              void* d_out, int out_size, void* d_ws, size_t ws_size,
                              hipStream_t stream)
{
    const float* x         = (const float*)d_in[0];
    const float* W         = (const float*)d_in[1];
    const float* bvec      = (const float*)d_in[2];
    const float* baselines = (const float*)d_in[3];
    float* out = (float*)d_out;
    float* seg = (float*)d_ws;   // 4*129*128*8*4B = 2.11 MiB

    osc1_kernel<<<BATCH*NOSC, 512, 0, stream>>>(x, W, bvec, baselines, seg);
    osc2_kernel<<<BATCH*128, 512, 0, stream>>>(seg, out);
}